// Round 5
// baseline (272.633 us; speedup 1.0000x reference)
//
#include <hip/hip_runtime.h>
#include <cstdint>
#include <cstddef>

#define NROWS 262144
#define EMB 256
#define NB 512
#define NCOPY 8
#define SLOPE 0.01f

typedef __attribute__((ext_vector_type(8))) short short8;
typedef __attribute__((ext_vector_type(4))) float f32x4;

__device__ __forceinline__ unsigned short f2bf(float f) {
    unsigned u = __float_as_uint(f);
    u += 0x7FFFu + ((u >> 16) & 1u);
    return (unsigned short)(u >> 16);
}

// async 16B global -> LDS (DMA, no VGPR round trip)
__device__ __forceinline__ void gld16(float* l, const float* g) {
    __builtin_amdgcn_global_load_lds(
        (const __attribute__((address_space(1))) unsigned int*)g,
        (__attribute__((address_space(3))) unsigned int*)l, 16, 0, 0);
}

// ---------- init: zero xgPart (8 copies) + dPart ----------
__global__ __launch_bounds__(256) void k_init(float4* xgPart4, float4* dPart4) {
    int i = blockIdx.x * 256 + threadIdx.x;
    if (i < NCOPY * NB * EMB / 4) xgPart4[i] = (float4){0.f, 0.f, 0.f, 0.f};
    else dPart4[i - NCOPY * NB * EMB / 4] = (float4){0.f, 0.f, 0.f, 0.f};
}

// ---------- prep: transpose W_feat -> bf16 Wt[col][k] ----------
__global__ __launch_bounds__(256) void k_prep(const float* __restrict__ Wf,
                                              unsigned short* __restrict__ Wt) {
    int b = blockIdx.x, t = threadIdx.x;
    float v = Wf[(size_t)b * EMB + t];   // W_feat[k=b][col=t]
    Wt[(size_t)t * EMB + b] = f2bf(v);   // Wt[col][k]
}

// A-fragment from swizzled LDS tile + gate partial + cvt to bf16
// LDS tile: [64 rows][16 chunks of 16B]; logical chunk c lives at slot c^(row&15)
__device__ __forceinline__ short8 afrag(const float* __restrict__ xb,
                                        const float* __restrict__ wms,
                                        int r, int sub, int fg, int kq, float& gp) {
    const int sl = (sub * 8 + fg * 2) ^ (r & 15);
    const float4 lo = *reinterpret_cast<const float4*>(&xb[r * 64 + sl * 4]);
    const float4 hi = *reinterpret_cast<const float4*>(&xb[r * 64 + (sl ^ 1) * 4]);
    const float4 wa = *reinterpret_cast<const float4*>(&wms[kq]);
    const float4 wb = *reinterpret_cast<const float4*>(&wms[kq + 4]);
    gp += lo.x * wa.x + lo.y * wa.y + lo.z * wa.z + lo.w * wa.w
        + hi.x * wb.x + hi.y * wb.y + hi.z * wb.z + hi.w * wb.w;
    short8 a;
    a[0] = (short)f2bf(lo.x); a[1] = (short)f2bf(lo.y);
    a[2] = (short)f2bf(lo.z); a[3] = (short)f2bf(lo.w);
    a[4] = (short)f2bf(hi.x); a[5] = (short)f2bf(hi.y);
    a[6] = (short)f2bf(hi.z); a[7] = (short)f2bf(hi.w);
    return a;
}

// ---------- fused: gate + exp + bf16 MFMA feat GEMM + weighted segment reduce ----------
// 256 threads (4 waves). Tile 64 rows x 256 cols. A staged via global_load_lds into
// double-buffered 64x64-f32 LDS tiles; B frags from L2 per K-step.
// Epilogue: LDS slot partials -> one flush per block into XCD-striped copies.
__global__ __launch_bounds__(256, 3) void k_fused(const float* __restrict__ x,
                                                  const unsigned short* __restrict__ Wt,
                                                  const float* __restrict__ wm,
                                                  const float* __restrict__ bfeat,
                                                  const int* __restrict__ bind,
                                                  float* __restrict__ dPart,
                                                  float* __restrict__ xgPart) {
    __shared__ float xbuf[2][64 * 64];   // 2 x 16KB
    __shared__ float wm_s[256];
    __shared__ float w_s[64];
    __shared__ float pxg[2][256];
    __shared__ float pden[2];
    __shared__ int   seg_s[64];
    __shared__ int   segid_s[4];
    __shared__ int   uni_s[4];

    const int t    = threadIdx.x;
    const int lane = t & 63;
    const int w    = t >> 6;
    const int wr   = w >> 1, wc = w & 1;
    const int fr   = lane & 15;
    const int fg   = lane >> 4;
    const size_t r0 = (size_t)blockIdx.x * 64;
    const int cp   = blockIdx.x & (NCOPY - 1);

    wm_s[t] = wm[t];
    pxg[0][t] = 0.f;
    pxg[1][t] = 0.f;
    if (t < 2) pden[t] = 0.f;
    if (t < 64) seg_s[t] = bind[r0 + t];

    // prologue stage: step 0 -> buf0 (pre-swizzled global source, linear LDS dest)
#pragma unroll
    for (int q = 0; q < 4; q++) {
        const int i = q * 256 + t;
        const int row = i >> 4;
        const int cs  = (i & 15) ^ (row & 15);
        gld16(&xbuf[0][i * 4], x + ((r0 + row) << 8) + (cs << 2));
    }
    __syncthreads();   // wm_s/seg_s/pxg visible + buf0 DMA drained

    const int sid0 = seg_s[0];
    const int sid1 = seg_s[63];

    if (t < 4) {
        int s0 = seg_s[t * 16], ok = 1;
#pragma unroll
        for (int i = 1; i < 16; i++) ok &= (seg_s[t * 16 + i] == s0);
        segid_s[t] = s0;
        uni_s[t]   = ok;
    }

    const unsigned short* wbase = Wt + (size_t)(wc * 128 + fr) * EMB + fg * 8;

    f32x4 acc[2][8];
#pragma unroll
    for (int m = 0; m < 2; m++)
#pragma unroll
        for (int n = 0; n < 8; n++) acc[m][n] = (f32x4){0.f, 0.f, 0.f, 0.f};
    float gp0 = 0.f, gp1 = 0.f;

    // main loop: 4 staging steps of K=64 (2 MFMA substeps each)
#pragma unroll
    for (int s = 0; s < 4; s++) {
        const int cur = s & 1;
        if (s < 3) {   // stage next step into other buffer
#pragma unroll
            for (int q = 0; q < 4; q++) {
                const int i = q * 256 + t;
                const int row = i >> 4;
                const int cs  = (i & 15) ^ (row & 15);
                gld16(&xbuf[cur ^ 1][i * 4],
                      x + ((r0 + row) << 8) + ((s + 1) << 6) + (cs << 2));
            }
        }
        const float* xb = &xbuf[cur][0];
        short8 b0[8], b1[8];
#pragma unroll
        for (int n = 0; n < 8; n++)
            b0[n] = *reinterpret_cast<const short8*>(wbase + n * 16 * EMB + s * 64);
#pragma unroll
        for (int n = 0; n < 8; n++)
            b1[n] = *reinterpret_cast<const short8*>(wbase + n * 16 * EMB + s * 64 + 32);

        {
            short8 a0 = afrag(xb, wm_s, wr * 32 + fr,      0, fg, s * 64 + fg * 8, gp0);
            short8 a1 = afrag(xb, wm_s, wr * 32 + 16 + fr, 0, fg, s * 64 + fg * 8, gp1);
#pragma unroll
            for (int n = 0; n < 8; n++) {
                acc[0][n] = __builtin_amdgcn_mfma_f32_16x16x32_bf16(a0, b0[n], acc[0][n], 0, 0, 0);
                acc[1][n] = __builtin_amdgcn_mfma_f32_16x16x32_bf16(a1, b0[n], acc[1][n], 0, 0, 0);
            }
        }
        {
            short8 a0 = afrag(xb, wm_s, wr * 32 + fr,      1, fg, s * 64 + 32 + fg * 8, gp0);
            short8 a1 = afrag(xb, wm_s, wr * 32 + 16 + fr, 1, fg, s * 64 + 32 + fg * 8, gp1);
#pragma unroll
            for (int n = 0; n < 8; n++) {
                acc[0][n] = __builtin_amdgcn_mfma_f32_16x16x32_bf16(a0, b1[n], acc[0][n], 0, 0, 0);
                acc[1][n] = __builtin_amdgcn_mfma_f32_16x16x32_bf16(a1, b1[n], acc[1][n], 0, 0, 0);
            }
        }
        __syncthreads();
    }

    // ---- gate -> e ----
    gp0 += __shfl_xor(gp0, 16, 64); gp0 += __shfl_xor(gp0, 32, 64);
    gp1 += __shfl_xor(gp1, 16, 64); gp1 += __shfl_xor(gp1, 32, 64);
    // exp(b_mask) cancels in the softmax -> dropped
    if (wc == 0 && lane < 16) {
        w_s[wr * 32 + lane]      = expf(gp0);
        w_s[wr * 32 + 16 + lane] = expf(gp1);
    }
    __syncthreads();

    // denom partials into LDS slots (global fallback for >2-segment blocks)
    if (t < 4) {
        if (uni_s[t]) {
            float s = 0.f;
#pragma unroll
            for (int i = 0; i < 16; i++) s += w_s[t * 16 + i];
            int sid = segid_s[t];
            if (sid == sid0)      atomicAdd(&pden[0], s);
            else if (sid == sid1) atomicAdd(&pden[1], s);
            else atomicAdd(&dPart[cp * NB + sid], s);
        } else {
            for (int i = 0; i < 16; i++) {
                int sd = seg_s[t * 16 + i];
                float e = w_s[t * 16 + i];
                if (sd == sid0)      atomicAdd(&pden[0], e);
                else if (sd == sid1) atomicAdd(&pden[1], e);
                else atomicAdd(&dPart[cp * NB + sd], e);
            }
        }
    }

    // ---- epilogue: bias -> leaky -> *e -> segmented reduce -> LDS slots ----
#pragma unroll
    for (int m = 0; m < 2; m++) {
        const int g    = wr * 2 + m;
        const int uni  = uni_s[g];
        const int sid  = segid_s[g];
        const int rowb = wr * 32 + m * 16;
#pragma unroll
        for (int n = 0; n < 8; n++) {
            const int col = wc * 128 + n * 16 + fr;
            const float bia = bfeat[col];
            float vr[4];
#pragma unroll
            for (int r = 0; r < 4; r++) {
                const int row = rowb + fg * 4 + r;
                float v = acc[m][n][r] + bia;
                v = (v >= 0.f) ? v : SLOPE * v;
                vr[r] = v * w_s[row];
            }
            if (uni) {
                float s = vr[0] + vr[1] + vr[2] + vr[3];
                s += __shfl_xor(s, 16, 64);
                s += __shfl_xor(s, 32, 64);
                if (fg == 0) {
                    if (sid == sid0)      atomicAdd(&pxg[0][col], s);
                    else if (sid == sid1) atomicAdd(&pxg[1][col], s);
                    else atomicAdd(&xgPart[((size_t)(cp * NB + sid) << 8) + col], s);
                }
            } else {
#pragma unroll
                for (int r = 0; r < 4; r++) {
                    const int sd = seg_s[rowb + fg * 4 + r];
                    if (sd == sid0)      atomicAdd(&pxg[0][col], vr[r]);
                    else if (sd == sid1) atomicAdd(&pxg[1][col], vr[r]);
                    else atomicAdd(&xgPart[((size_t)(cp * NB + sd) << 8) + col], vr[r]);
                }
            }
        }
    }
    __syncthreads();

    // ---- flush block partials into XCD-striped copies ----
    atomicAdd(&xgPart[((size_t)(cp * NB + sid0) << 8) + t], pxg[0][t]);
    if (sid1 != sid0)
        atomicAdd(&xgPart[((size_t)(cp * NB + sid1) << 8) + t], pxg[1][t]);
    if (t == 0) atomicAdd(&dPart[cp * NB + sid0], pden[0]);
    if (t == 1 && sid1 != sid0) atomicAdd(&dPart[cp * NB + sid1], pden[1]);
}

// ---------- out = leaky_relu([xg/denom, xg_prev] @ W_t + b_t) + xg_prev ----------
__global__ __launch_bounds__(256) void k_out(const float* __restrict__ xgPart,
                                             const float* __restrict__ dPart,
                                             const float* __restrict__ xgp,
                                             const float* __restrict__ Wtr,
                                             const float* __restrict__ bt,
                                             float* __restrict__ out) {
    __shared__ float h[8][512];
    const int c  = threadIdx.x;
    const int b0 = blockIdx.x * 8;
#pragma unroll
    for (int r = 0; r < 8; r++) {
        const int b = b0 + r;
        float den = 0.f, s = 0.f;
#pragma unroll
        for (int cpy = 0; cpy < NCOPY; cpy++) {
            den += dPart[cpy * NB + b];
            s   += xgPart[((size_t)(cpy * NB + b) << 8) + c];
        }
        h[r][c]       = s / fmaxf(den, 1e-16f);
        h[r][EMB + c] = xgp[(size_t)b * EMB + c];
    }
    __syncthreads();
    float acc[8] = {0.f, 0.f, 0.f, 0.f, 0.f, 0.f, 0.f, 0.f};
    for (int k = 0; k < 2 * EMB; k++) {
        float wv = Wtr[(size_t)k * EMB + c];
#pragma unroll
        for (int r = 0; r < 8; r++) acc[r] += h[r][k] * wv;
    }
#pragma unroll
    for (int r = 0; r < 8; r++) {
        float v = acc[r] + bt[c];
        v = (v >= 0.f) ? v : SLOPE * v;
        out[(size_t)(b0 + r) * EMB + c] = v + xgp[(size_t)(b0 + r) * EMB + c];
    }
}

extern "C" void kernel_launch(void* const* d_in, const int* in_sizes, int n_in,
                              void* d_out, int out_size, void* d_ws, size_t ws_size,
                              hipStream_t stream) {
    const float* xgp  = (const float*)d_in[0];
    const float* x    = (const float*)d_in[1];
    const int*   bind = (const int*)d_in[2];
    const float* Wm   = (const float*)d_in[3];
    const float* Wf   = (const float*)d_in[5];
    const float* bf   = (const float*)d_in[6];
    const float* Wtr  = (const float*)d_in[7];
    const float* bt   = (const float*)d_in[8];
    float* out = (float*)d_out;

    char* ws = (char*)d_ws;
    unsigned short* Wt     = (unsigned short*)ws;                 // 128 KB
    float*          dPart  = (float*)(ws + 131072);               // 8*512 f32 = 16 KB
    float*          xgPart = (float*)(ws + 131072 + 16384);       // 8*512*256 f32 = 4 MB

    // zero 8*512*256 + 8*512 floats = 263168 float4s -> 1028 blocks
    hipLaunchKernelGGL(k_init,  dim3(1028),       dim3(256), 0, stream,
                       (float4*)xgPart, (float4*)dPart);
    hipLaunchKernelGGL(k_prep,  dim3(256),        dim3(256), 0, stream, Wf, Wt);
    hipLaunchKernelGGL(k_fused, dim3(NROWS / 64), dim3(256), 0, stream,
                       x, Wt, Wm, bf, bind, dPart, xgPart);
    hipLaunchKernelGGL(k_out,   dim3(NB / 8),     dim3(256), 0, stream,
                       xgPart, dPart, xgp, Wtr, bt, out);
}